// Round 9
// baseline (262.826 us; speedup 1.0000x reference)
//
#include <hip/hip_runtime.h>

typedef __bf16 bf16x8 __attribute__((ext_vector_type(8)));
typedef float f32x4 __attribute__((ext_vector_type(4)));

#define DIM 1024
#define NSEQ 2048

// async 16B global -> LDS DMA (lane-linear: wave-uniform LDS base + lane*16)
#define GL2LDS(g, l) __builtin_amdgcn_global_load_lds( \
    (const __attribute__((address_space(1))) void*)(g), \
    (__attribute__((address_space(3))) void*)(l), 16, 0, 0)

// ---------------- fp32 -> bf16 weight conversion ----------------
__global__ __launch_bounds__(256) void cvt_kernel(const float* __restrict__ s,
                                                  __bf16* __restrict__ d) {
    int i = (blockIdx.x * 256 + threadIdx.x) * 4;
    float4 f = *(const float4*)(s + i);
    union { uint2 u; __bf16 h[4]; } p;
    p.h[0] = (__bf16)f.x; p.h[1] = (__bf16)f.y;
    p.h[2] = (__bf16)f.z; p.h[3] = (__bf16)f.w;
    *(uint2*)(d + i) = p.u;
}

// ---------------- RMSNorm: fp32 in, bf16 out ----------------
__global__ __launch_bounds__(256) void rmsnorm_kernel(const float* __restrict__ x,
                                                      const float* __restrict__ g,
                                                      __bf16* __restrict__ o) {
    int row = blockIdx.x;
    int t = threadIdx.x;
    float4 xv = ((const float4*)(x + (size_t)row * DIM))[t];
    float ss = xv.x*xv.x + xv.y*xv.y + xv.z*xv.z + xv.w*xv.w;
    #pragma unroll
    for (int off = 32; off; off >>= 1) ss += __shfl_xor(ss, off, 64);
    __shared__ float red[4];
    if ((t & 63) == 0) red[t >> 6] = ss;
    __syncthreads();
    ss = red[0] + red[1] + red[2] + red[3];
    float r = rsqrtf(ss * (1.0f / 1024.0f) + 1.1920929e-07f);
    float4 gv = ((const float4*)g)[t];
    union { uint2 u; __bf16 h[4]; } p;
    p.h[0] = (__bf16)(xv.x * r * gv.x);
    p.h[1] = (__bf16)(xv.y * r * gv.y);
    p.h[2] = (__bf16)(xv.z * r * gv.z);
    p.h[3] = (__bf16)(xv.w * r * gv.w);
    *(uint2*)(o + (size_t)row * DIM + t * 4) = p.u;
}

// ---------------- RoPE in-place on (4096 x 1024) bf16, heads of 64 ----------------
__global__ __launch_bounds__(256) void rope_kernel(__bf16* __restrict__ x) {
    int gid = blockIdx.x * 256 + threadIdx.x;   // one pair per thread
    int row = gid >> 9;          // 512 pairs per row
    int pr = gid & 511;
    int pos = row & (NSEQ - 1);
    int dp = pr & 31;            // pair index within head
    float inv = __expf(-(float)dp * (9.210340371976184f / 32.0f)); // 10000^(-2dp/64)
    float ang = (float)pos * inv;
    float sn, cs;
    sincosf(ang, &sn, &cs);
    size_t off = (size_t)row * DIM + pr * 2;
    union { unsigned int u; __bf16 h[2]; } p;
    p.u = *(const unsigned int*)(x + off);
    float x1 = (float)p.h[0], x2 = (float)p.h[1];
    p.h[0] = (__bf16)(x1 * cs - x2 * sn);
    p.h[1] = (__bf16)(x2 * cs + x1 * sn);
    *(unsigned int*)(x + off) = p.u;
}

// ---------------- GEMM (m97 structure): C[i,j] = scale * sum_k A[i,k]*B[j,k] ----
// A: M x 1024 bf16; B: N x 1024 bf16 (or fp32, VGPR-staged); C: bf16/fp32, ldc.
// 128x128 tile, BK=32, UNPADDED stride-32 LDS tiles filled by global_load_lds
// (lane-linear layout), single buffer, 2 barriers per K-tile.
template <typename BT, typename CT>
__global__ __launch_bounds__(256) void gemm_bt_kernel(const __bf16* __restrict__ A,
                                                      const BT* __restrict__ B,
                                                      CT* __restrict__ C,
                                                      float scale, int ldc) {
    __shared__ __bf16 As[128 * 32];
    __shared__ __bf16 Bs[128 * 32];
    int bm = blockIdx.x, bn = blockIdx.y;
    int t = threadIdx.x;
    int w = t >> 6, l = t & 63;
    int wm = (w >> 1) * 64, wn = (w & 1) * 64;   // wave 2x2 grid, each 64x64
    int lrow = l & 15, lq = l >> 4;
    f32x4 acc[4][4] = {};

    // DMA staging geometry: call c, wave w, lane l covers tile row
    // c*64 + w*16 + (l>>2), 8-elem col block (l&3). LDS base per (c,w) is
    // lane-uniform; HW adds lane*16B.
    int srow = w * 16 + (l >> 2);                // + c*64
    int sc8 = (l & 3) * 8;
    const __bf16* gA = A + (size_t)(bm * 128 + srow) * 1024 + sc8;
    __bf16* lA = As + (w * 64) * 8;              // slot*(8 bf16) ; + c*256*8

    for (int kt = 0; kt < 32; ++kt) {
        int k0 = kt * 32;
        // stage A via async DMA (2 calls/wave)
        GL2LDS(gA + k0, lA);
        GL2LDS(gA + k0 + (size_t)64 * 1024, lA + 256 * 8);
        // stage B
        if constexpr (sizeof(BT) == 2) {
            const __bf16* gB = (const __bf16*)B + (size_t)(bn * 128 + srow) * 1024 + sc8;
            __bf16* lB = Bs + (w * 64) * 8;
            GL2LDS(gB + k0, lB);
            GL2LDS(gB + k0 + (size_t)64 * 1024, lB + 256 * 8);
        } else {
            // fp32 weights: VGPR-stage + convert (final GEMM only)
            #pragma unroll
            for (int it = 0; it < 4; ++it) {
                int idx = t + it * 256;          // 1024 x 16B covers 128x32 fp32
                int row = idx >> 3;
                int c4 = (idx & 7) * 4;
                float4 f = *(const float4*)((const float*)B + (size_t)(bn * 128 + row) * 1024 + k0 + c4);
                union { uint2 u2; __bf16 h[4]; } pk;
                pk.h[0] = (__bf16)f.x; pk.h[1] = (__bf16)f.y;
                pk.h[2] = (__bf16)f.z; pk.h[3] = (__bf16)f.w;
                *(uint2*)&Bs[row * 32 + c4] = pk.u2;
            }
        }
        __syncthreads();    // drains DMA (vmcnt) + LDS stores, publishes tile
        bf16x8 af[4], bfr[4];
        #pragma unroll
        for (int i = 0; i < 4; ++i)
            af[i] = *(const bf16x8*)&As[(wm + i * 16 + lrow) * 32 + lq * 8];
        #pragma unroll
        for (int i = 0; i < 4; ++i)
            bfr[i] = *(const bf16x8*)&Bs[(wn + i * 16 + lrow) * 32 + lq * 8];
        #pragma unroll
        for (int rt = 0; rt < 4; ++rt)
            #pragma unroll
            for (int ct = 0; ct < 4; ++ct)
                acc[rt][ct] = __builtin_amdgcn_mfma_f32_16x16x32_bf16(
                    af[rt], bfr[ct], acc[rt][ct], 0, 0, 0);
        __syncthreads();    // all waves done reading before next overwrite
    }
    #pragma unroll
    for (int rt = 0; rt < 4; ++rt)
        #pragma unroll
        for (int ct = 0; ct < 4; ++ct)
            #pragma unroll
            for (int r = 0; r < 4; ++r) {
                int row = bm * 128 + wm + rt * 16 + lq * 4 + r;   // C-layout
                int col = bn * 128 + wn + ct * 16 + lrow;
                C[(size_t)row * ldc + col] = (CT)(acc[rt][ct][r] * scale);
            }
}

// ---------------- Causal flash attention (S^T formulation) — round-8, 74 µs ----
__global__ __launch_bounds__(256, 4) void attn_kernel(const __bf16* __restrict__ q,
                                                      const __bf16* __restrict__ kk,
                                                      const __bf16* __restrict__ vt,
                                                      __bf16* __restrict__ o) {
    int blk = blockIdx.x;
    int qt = 31 - (blk & 31);            // long blocks first
    int h = (blk >> 5) & 15;
    int b = blk >> 9;
    int rowbase = b * NSEQ;
    int t = threadIdx.x;
    int w = t >> 6, l = t & 63;
    int lrow = l & 15, lq = l >> 4;

    __shared__ __bf16 Kt[64 * 72];       // [key][d], stride 72
    __shared__ __bf16 Vs[64 * 72];       // [d][key], stride 72 (from vt)
    __shared__ __bf16 Ps[4 * 16 * 72];   // per-wave P^T strip as [qrow][key]
    __bf16* pw = &Ps[w * 16 * 72];

    const __bf16* kbase = kk + (size_t)rowbase * DIM + h * 64;
    const __bf16* vbase = vt + (size_t)(h * 64) * 4096 + b * 2048;

    int row0 = t >> 3;
    int c8 = (t & 7) * 8;

    const __bf16* qp = q + (size_t)(rowbase + qt * 64 + w * 16 + lrow) * DIM + h * 64;
    bf16x8 qb0 = *(const bf16x8*)(qp + lq * 8);
    bf16x8 qb1 = *(const bf16x8*)(qp + 32 + lq * 8);

    f32x4 oacc[4] = {};
    float m_r = -1e30f, l_r = 0.0f;

    uint4 kr0, kr1, vr0, vr1;
    kr0 = *(const uint4*)(kbase + (size_t)row0 * DIM + c8);
    kr1 = *(const uint4*)(kbase + (size_t)(row0 + 32) * DIM + c8);
    vr0 = *(const uint4*)(vbase + (size_t)row0 * 4096 + c8);
    vr1 = *(const uint4*)(vbase + (size_t)(row0 + 32) * 4096 + c8);
    *(uint4*)&Kt[row0 * 72 + c8] = kr0;
    *(uint4*)&Kt[(row0 + 32) * 72 + c8] = kr1;
    *(uint4*)&Vs[row0 * 72 + c8] = vr0;
    *(uint4*)&Vs[(row0 + 32) * 72 + c8] = vr1;
    __syncthreads();

    for (int jt = 0; jt <= qt; ++jt) {
        if (jt < qt) {
            int j0 = (jt + 1) * 64;
            kr0 = *(const uint4*)(kbase + (size_t)(j0 + row0) * DIM + c8);
            kr1 = *(const uint4*)(kbase + (size_t)(j0 + row0 + 32) * DIM + c8);
            vr0 = *(const uint4*)(vbase + (size_t)row0 * 4096 + j0 + c8);
            vr1 = *(const uint4*)(vbase + (size_t)(row0 + 32) * 4096 + j0 + c8);
        }

        f32x4 st[4];
        #pragma unroll
        for (int ct = 0; ct < 4; ++ct) {
            f32x4 z = {};
            bf16x8 ka0 = *(const bf16x8*)&Kt[(ct * 16 + lrow) * 72 + lq * 8];
            bf16x8 ka1 = *(const bf16x8*)&Kt[(ct * 16 + lrow) * 72 + 32 + lq * 8];
            z = __builtin_amdgcn_mfma_f32_16x16x32_bf16(ka0, qb0, z, 0, 0, 0);
            z = __builtin_amdgcn_mfma_f32_16x16x32_bf16(ka1, qb1, z, 0, 0, 0);
            st[ct] = z;
        }
        if (jt == qt) {
            int qr = w * 16 + lrow;
            #pragma unroll
            for (int ct = 0; ct < 4; ++ct)
                #pragma unroll
                for (int r = 0; r < 4; ++r)
                    if (ct * 16 + lq * 4 + r > qr) st[ct][r] = -3.0e38f;
        }
        float mx = st[0][0];
        #pragma unroll
        for (int ct = 0; ct < 4; ++ct)
            #pragma unroll
            for (int r = 0; r < 4; ++r) mx = fmaxf(mx, st[ct][r]);
        mx = fmaxf(mx, __shfl_xor(mx, 16, 64));
        mx = fmaxf(mx, __shfl_xor(mx, 32, 64));
        float mnew = fmaxf(m_r, mx);
        float alpha = __expf(m_r - mnew);
        float ps = 0.0f;
        #pragma unroll
        for (int ct = 0; ct < 4; ++ct)
            #pragma unroll
            for (int r = 0; r < 4; ++r) {
                float p = __expf(st[ct][r] - mnew);
                st[ct][r] = p;
                ps += p;
            }
        ps += __shfl_xor(ps, 16, 64);
        ps += __shfl_xor(ps, 32, 64);
        l_r = l_r * alpha + ps;
        m_r = mnew;

        #pragma unroll
        for (int ct = 0; ct < 4; ++ct)
            #pragma unroll
            for (int r = 0; r < 4; ++r)
                pw[lrow * 72 + ct * 16 + lq * 4 + r] = (__bf16)st[ct][r];
        #pragma unroll
        for (int ct = 0; ct < 4; ++ct)
            #pragma unroll
            for (int r = 0; r < 4; ++r) oacc[ct][r] *= alpha;
        bf16x8 pb0 = *(const bf16x8*)&pw[lrow * 72 + lq * 8];
        bf16x8 pb1 = *(const bf16x8*)&pw[lrow * 72 + 32 + lq * 8];
        #pragma unroll
        for (int ct = 0; ct < 4; ++ct) {
            bf16x8 va0 = *(const bf16x8*)&Vs[(ct * 16 + lrow) * 72 + lq * 8];
            bf16x8 va1 = *(const bf16x8*)&Vs[(ct * 16 + lrow) * 72 + 32 + lq * 8];
            oacc[ct] = __builtin_amdgcn_mfma_f32_16x16x32_bf16(va0, pb0, oacc[ct], 0, 0, 0);
            oacc[ct] = __builtin_amdgcn_mfma_f32_16x16x32_bf16(va1, pb1, oacc[ct], 0, 0, 0);
        }
        __syncthreads();
        if (jt < qt) {
            *(uint4*)&Kt[row0 * 72 + c8] = kr0;
            *(uint4*)&Kt[(row0 + 32) * 72 + c8] = kr1;
            *(uint4*)&Vs[row0 * 72 + c8] = vr0;
            *(uint4*)&Vs[(row0 + 32) * 72 + c8] = vr1;
        }
        __syncthreads();
    }
    float rcp = 1.0f / l_r;
    const size_t orow = (size_t)(rowbase + qt * 64 + w * 16 + lrow) * DIM + h * 64;
    #pragma unroll
    for (int ct = 0; ct < 4; ++ct) {
        union { uint2 u; __bf16 h4[4]; } pk;
        #pragma unroll
        for (int r = 0; r < 4; ++r) pk.h4[r] = (__bf16)(oacc[ct][r] * rcp);
        *(uint2*)(o + orow + ct * 16 + lq * 4) = pk.u;
    }
}

extern "C" void kernel_launch(void* const* d_in, const int* in_sizes, int n_in,
                              void* d_out, int out_size, void* d_ws, size_t ws_size,
                              hipStream_t stream) {
    const float* tokens = (const float*)d_in[0];
    const float* gamma  = (const float*)d_in[1];
    const float* wq = (const float*)d_in[2];
    const float* wk = (const float*)d_in[3];
    const float* wv = (const float*)d_in[4];
    const float* wo = (const float*)d_in[5];

    __bf16* ws  = (__bf16*)d_ws;
    __bf16* x   = ws;                           // 4096*1024 (dead after V^T GEMM)
    __bf16* qb  = x   + (size_t)4096 * 1024;
    __bf16* kb  = qb  + (size_t)4096 * 1024;
    __bf16* vtb = kb  + (size_t)4096 * 1024;    // V^T: 1024 x 4096
    __bf16* ao  = x;                            // alias: attn out reuses x's buffer
    float*  out = (float*)d_out;

    // bf16 weights stashed in d_out (written only by the final GEMM -> no race)
    __bf16* wqb = (__bf16*)d_out;
    __bf16* wkb = wqb + (size_t)1024 * 1024;
    __bf16* wvb = wkb + (size_t)1024 * 1024;

    cvt_kernel<<<1024, 256, 0, stream>>>(wq, wqb);
    cvt_kernel<<<1024, 256, 0, stream>>>(wk, wkb);
    cvt_kernel<<<1024, 256, 0, stream>>>(wv, wvb);

    rmsnorm_kernel<<<4096, 256, 0, stream>>>(tokens, gamma, x);

    dim3 gg(32, 8);
    gemm_bt_kernel<__bf16, __bf16><<<gg, 256, 0, stream>>>(x, wqb, qb, 0.125f, 1024);
    gemm_bt_kernel<__bf16, __bf16><<<gg, 256, 0, stream>>>(x, wkb, kb, 1.0f, 1024);
    // V^T directly: C'[j,i] = sum_k wv[j,k] x[i,k]  ->  vt (1024 x 4096)
    dim3 gv(8, 32);
    gemm_bt_kernel<__bf16, __bf16><<<gv, 256, 0, stream>>>(wvb, x, vtb, 1.0f, 4096);

    rope_kernel<<<8192, 256, 0, stream>>>(qb);
    rope_kernel<<<8192, 256, 0, stream>>>(kb);

    attn_kernel<<<1024, 256, 0, stream>>>(qb, kb, vtb, ao);

    gemm_bt_kernel<float, float><<<gg, 256, 0, stream>>>(ao, wo, out, 1.0f, 1024);
}

// Round 10
// 224.589 us; speedup vs baseline: 1.1703x; 1.1703x over previous
//
#include <hip/hip_runtime.h>

typedef __bf16 bf16x8 __attribute__((ext_vector_type(8)));
typedef float f32x4 __attribute__((ext_vector_type(4)));

#define DIM 1024
#define NSEQ 2048

// async 16B global -> LDS DMA (lane-linear: wave-uniform LDS base + lane*16)
#define GL2LDS(g, l) __builtin_amdgcn_global_load_lds( \
    (const __attribute__((address_space(1))) void*)(g), \
    (__attribute__((address_space(3))) void*)(l), 16, 0, 0)

// ---------------- fp32 -> bf16 weight conversion ----------------
__global__ __launch_bounds__(256) void cvt_kernel(const float* __restrict__ s,
                                                  __bf16* __restrict__ d) {
    int i = (blockIdx.x * 256 + threadIdx.x) * 4;
    float4 f = *(const float4*)(s + i);
    union { uint2 u; __bf16 h[4]; } p;
    p.h[0] = (__bf16)f.x; p.h[1] = (__bf16)f.y;
    p.h[2] = (__bf16)f.z; p.h[3] = (__bf16)f.w;
    *(uint2*)(d + i) = p.u;
}

// ---------------- RMSNorm: fp32 in, bf16 out ----------------
__global__ __launch_bounds__(256) void rmsnorm_kernel(const float* __restrict__ x,
                                                      const float* __restrict__ g,
                                                      __bf16* __restrict__ o) {
    int row = blockIdx.x;
    int t = threadIdx.x;
    float4 xv = ((const float4*)(x + (size_t)row * DIM))[t];
    float ss = xv.x*xv.x + xv.y*xv.y + xv.z*xv.z + xv.w*xv.w;
    #pragma unroll
    for (int off = 32; off; off >>= 1) ss += __shfl_xor(ss, off, 64);
    __shared__ float red[4];
    if ((t & 63) == 0) red[t >> 6] = ss;
    __syncthreads();
    ss = red[0] + red[1] + red[2] + red[3];
    float r = rsqrtf(ss * (1.0f / 1024.0f) + 1.1920929e-07f);
    float4 gv = ((const float4*)g)[t];
    union { uint2 u; __bf16 h[4]; } p;
    p.h[0] = (__bf16)(xv.x * r * gv.x);
    p.h[1] = (__bf16)(xv.y * r * gv.y);
    p.h[2] = (__bf16)(xv.z * r * gv.z);
    p.h[3] = (__bf16)(xv.w * r * gv.w);
    *(uint2*)(o + (size_t)row * DIM + t * 4) = p.u;
}

// ---------------- RoPE in-place on (4096 x 1024) bf16, heads of 64 ----------------
__global__ __launch_bounds__(256) void rope_kernel(__bf16* __restrict__ x) {
    int gid = blockIdx.x * 256 + threadIdx.x;   // one pair per thread
    int row = gid >> 9;          // 512 pairs per row
    int pr = gid & 511;
    int pos = row & (NSEQ - 1);
    int dp = pr & 31;            // pair index within head
    float inv = __expf(-(float)dp * (9.210340371976184f / 32.0f)); // 10000^(-2dp/64)
    float ang = (float)pos * inv;
    float sn, cs;
    sincosf(ang, &sn, &cs);
    size_t off = (size_t)row * DIM + pr * 2;
    union { unsigned int u; __bf16 h[2]; } p;
    p.u = *(const unsigned int*)(x + off);
    float x1 = (float)p.h[0], x2 = (float)p.h[1];
    p.h[0] = (__bf16)(x1 * cs - x2 * sn);
    p.h[1] = (__bf16)(x2 * cs + x1 * sn);
    *(unsigned int*)(x + off) = p.u;
}

// ---------------- shared GEMM body: C[i,j] = scale*sum_k A[mb*128+i,k]B[nb*128+j,k]
// 128x128 tile, BK=32, unpadded stride-32 LDS via global_load_lds, 2 barriers/tile.
template <typename CT>
__device__ __forceinline__ void gemm_body(const __bf16* __restrict__ A,
                                          const __bf16* __restrict__ B,
                                          CT* __restrict__ C,
                                          int mb, int nb, int ldc, float scale,
                                          __bf16* As, __bf16* Bs) {
    int t = threadIdx.x;
    int w = t >> 6, l = t & 63;
    int wm = (w >> 1) * 64, wn = (w & 1) * 64;   // wave 2x2 grid, each 64x64
    int lrow = l & 15, lq = l >> 4;
    f32x4 acc[4][4] = {};

    int srow = w * 16 + (l >> 2);                // DMA: + c*64
    int sc8 = (l & 3) * 8;
    const __bf16* gA = A + (size_t)(mb * 128 + srow) * 1024 + sc8;
    const __bf16* gB = B + (size_t)(nb * 128 + srow) * 1024 + sc8;
    __bf16* lA = As + (w * 64) * 8;              // lane-linear slots; + c*256*8
    __bf16* lB = Bs + (w * 64) * 8;

    for (int kt = 0; kt < 32; ++kt) {
        int k0 = kt * 32;
        GL2LDS(gA + k0, lA);
        GL2LDS(gA + k0 + (size_t)64 * 1024, lA + 256 * 8);
        GL2LDS(gB + k0, lB);
        GL2LDS(gB + k0 + (size_t)64 * 1024, lB + 256 * 8);
        __syncthreads();    // drains DMA, publishes tile
        bf16x8 af[4], bfr[4];
        #pragma unroll
        for (int i = 0; i < 4; ++i)
            af[i] = *(const bf16x8*)&As[(wm + i * 16 + lrow) * 32 + lq * 8];
        #pragma unroll
        for (int i = 0; i < 4; ++i)
            bfr[i] = *(const bf16x8*)&Bs[(wn + i * 16 + lrow) * 32 + lq * 8];
        #pragma unroll
        for (int rt = 0; rt < 4; ++rt)
            #pragma unroll
            for (int ct = 0; ct < 4; ++ct)
                acc[rt][ct] = __builtin_amdgcn_mfma_f32_16x16x32_bf16(
                    af[rt], bfr[ct], acc[rt][ct], 0, 0, 0);
        __syncthreads();
    }
    #pragma unroll
    for (int rt = 0; rt < 4; ++rt)
        #pragma unroll
        for (int ct = 0; ct < 4; ++ct)
            #pragma unroll
            for (int r = 0; r < 4; ++r) {
                int row = mb * 128 + wm + rt * 16 + lq * 4 + r;   // C-layout
                int col = nb * 128 + wn + ct * 16 + lrow;
                C[(size_t)row * ldc + col] = (CT)(acc[rt][ct][r] * scale);
            }
}

// Fused QKV projections: grid (32, 8, 3) -> 768 blocks = 3 blocks/CU for
// cross-block barrier-drain overlap. z=0: Q (scaled), z=1: K, z=2: V^T (swapped).
__global__ __launch_bounds__(256) void qkv_kernel(const __bf16* __restrict__ x,
                                                  const __bf16* __restrict__ wq,
                                                  const __bf16* __restrict__ wk,
                                                  const __bf16* __restrict__ wv,
                                                  __bf16* __restrict__ qb,
                                                  __bf16* __restrict__ kb,
                                                  __bf16* __restrict__ vtb) {
    __shared__ __bf16 As[128 * 32];
    __shared__ __bf16 Bs[128 * 32];
    int bm = blockIdx.x, bn = blockIdx.y, z = blockIdx.z;
    if (z == 0)      gemm_body<__bf16>(x,  wq, qb,  bm, bn, 1024, 0.125f, As, Bs);
    else if (z == 1) gemm_body<__bf16>(x,  wk, kb,  bm, bn, 1024, 1.0f,   As, Bs);
    else             gemm_body<__bf16>(wv, x,  vtb, bn, bm, 4096, 1.0f,   As, Bs);
}

// Output projection: all-bf16 DMA path, fp32 store.
__global__ __launch_bounds__(256) void wo_kernel(const __bf16* __restrict__ A,
                                                 const __bf16* __restrict__ B,
                                                 float* __restrict__ C) {
    __shared__ __bf16 As[128 * 32];
    __shared__ __bf16 Bs[128 * 32];
    gemm_body<float>(A, B, C, blockIdx.x, blockIdx.y, 1024, 1.0f, As, Bs);
}

// ---------------- Causal flash attention (S^T formulation) ----------------
__global__ __launch_bounds__(256, 4) void attn_kernel(const __bf16* __restrict__ q,
                                                      const __bf16* __restrict__ kk,
                                                      const __bf16* __restrict__ vt,
                                                      __bf16* __restrict__ o) {
    int blk = blockIdx.x;
    int qt = 31 - (blk & 31);            // long blocks first
    int h = (blk >> 5) & 15;
    int b = blk >> 9;
    int rowbase = b * NSEQ;
    int t = threadIdx.x;
    int w = t >> 6, l = t & 63;
    int lrow = l & 15, lq = l >> 4;

    __shared__ __bf16 Kt[64 * 72];       // [key][d], stride 72
    __shared__ __bf16 Vs[64 * 72];       // [d][key], stride 72 (from vt)
    __shared__ __bf16 Ps[4 * 16 * 72];   // per-wave P^T strip as [qrow][key]
    __bf16* pw = &Ps[w * 16 * 72];

    const __bf16* kbase = kk + (size_t)rowbase * DIM + h * 64;
    const __bf16* vbase = vt + (size_t)(h * 64) * 4096 + b * 2048;

    int row0 = t >> 3;
    int c8 = (t & 7) * 8;

    const __bf16* qp = q + (size_t)(rowbase + qt * 64 + w * 16 + lrow) * DIM + h * 64;
    bf16x8 qb0 = *(const bf16x8*)(qp + lq * 8);
    bf16x8 qb1 = *(const bf16x8*)(qp + 32 + lq * 8);

    f32x4 oacc[4] = {};
    float m_r = -1e30f, l_r = 0.0f;

    uint4 kr0, kr1, vr0, vr1;
    kr0 = *(const uint4*)(kbase + (size_t)row0 * DIM + c8);
    kr1 = *(const uint4*)(kbase + (size_t)(row0 + 32) * DIM + c8);
    vr0 = *(const uint4*)(vbase + (size_t)row0 * 4096 + c8);
    vr1 = *(const uint4*)(vbase + (size_t)(row0 + 32) * 4096 + c8);
    *(uint4*)&Kt[row0 * 72 + c8] = kr0;
    *(uint4*)&Kt[(row0 + 32) * 72 + c8] = kr1;
    *(uint4*)&Vs[row0 * 72 + c8] = vr0;
    *(uint4*)&Vs[(row0 + 32) * 72 + c8] = vr1;
    __syncthreads();

    for (int jt = 0; jt <= qt; ++jt) {
        if (jt < qt) {
            int j0 = (jt + 1) * 64;
            kr0 = *(const uint4*)(kbase + (size_t)(j0 + row0) * DIM + c8);
            kr1 = *(const uint4*)(kbase + (size_t)(j0 + row0 + 32) * DIM + c8);
            vr0 = *(const uint4*)(vbase + (size_t)row0 * 4096 + j0 + c8);
            vr1 = *(const uint4*)(vbase + (size_t)(row0 + 32) * 4096 + j0 + c8);
        }

        f32x4 st[4];
        #pragma unroll
        for (int ct = 0; ct < 4; ++ct) {
            f32x4 z = {};
            bf16x8 ka0 = *(const bf16x8*)&Kt[(ct * 16 + lrow) * 72 + lq * 8];
            bf16x8 ka1 = *(const bf16x8*)&Kt[(ct * 16 + lrow) * 72 + 32 + lq * 8];
            z = __builtin_amdgcn_mfma_f32_16x16x32_bf16(ka0, qb0, z, 0, 0, 0);
            z = __builtin_amdgcn_mfma_f32_16x16x32_bf16(ka1, qb1, z, 0, 0, 0);
            st[ct] = z;
        }
        if (jt == qt) {
            int qr = w * 16 + lrow;
            #pragma unroll
            for (int ct = 0; ct < 4; ++ct)
                #pragma unroll
                for (int r = 0; r < 4; ++r)
                    if (ct * 16 + lq * 4 + r > qr) st[ct][r] = -3.0e38f;
        }
        float mx = st[0][0];
        #pragma unroll
        for (int ct = 0; ct < 4; ++ct)
            #pragma unroll
            for (int r = 0; r < 4; ++r) mx = fmaxf(mx, st[ct][r]);
        mx = fmaxf(mx, __shfl_xor(mx, 16, 64));
        mx = fmaxf(mx, __shfl_xor(mx, 32, 64));
        float mnew = fmaxf(m_r, mx);
        float alpha = __expf(m_r - mnew);
        float ps = 0.0f;
        #pragma unroll
        for (int ct = 0; ct < 4; ++ct)
            #pragma unroll
            for (int r = 0; r < 4; ++r) {
                float p = __expf(st[ct][r] - mnew);
                st[ct][r] = p;
                ps += p;
            }
        ps += __shfl_xor(ps, 16, 64);
        ps += __shfl_xor(ps, 32, 64);
        l_r = l_r * alpha + ps;
        m_r = mnew;

        // P^T -> per-wave LDS strip, 4x ds_write_b64 (was 16x b16)
        #pragma unroll
        for (int ct = 0; ct < 4; ++ct) {
            union { uint2 u; __bf16 h4[4]; } pk;
            #pragma unroll
            for (int r = 0; r < 4; ++r) pk.h4[r] = (__bf16)st[ct][r];
            *(uint2*)&pw[lrow * 72 + ct * 16 + lq * 4] = pk.u;
        }
        #pragma unroll
        for (int ct = 0; ct < 4; ++ct)
            #pragma unroll
            for (int r = 0; r < 4; ++r) oacc[ct][r] *= alpha;
        bf16x8 pb0 = *(const bf16x8*)&pw[lrow * 72 + lq * 8];
        bf16x8 pb1 = *(const bf16x8*)&pw[lrow * 72 + 32 + lq * 8];
        #pragma unroll
        for (int ct = 0; ct < 4; ++ct) {
            bf16x8 va0 = *(const bf16x8*)&Vs[(ct * 16 + lrow) * 72 + lq * 8];
            bf16x8 va1 = *(const bf16x8*)&Vs[(ct * 16 + lrow) * 72 + 32 + lq * 8];
            oacc[ct] = __builtin_amdgcn_mfma_f32_16x16x32_bf16(va0, pb0, oacc[ct], 0, 0, 0);
            oacc[ct] = __builtin_amdgcn_mfma_f32_16x16x32_bf16(va1, pb1, oacc[ct], 0, 0, 0);
        }
        __syncthreads();
        if (jt < qt) {
            *(uint4*)&Kt[row0 * 72 + c8] = kr0;
            *(uint4*)&Kt[(row0 + 32) * 72 + c8] = kr1;
            *(uint4*)&Vs[row0 * 72 + c8] = vr0;
            *(uint4*)&Vs[(row0 + 32) * 72 + c8] = vr1;
        }
        __syncthreads();
    }
    float rcp = 1.0f / l_r;
    const size_t orow = (size_t)(rowbase + qt * 64 + w * 16 + lrow) * DIM + h * 64;
    #pragma unroll
    for (int ct = 0; ct < 4; ++ct) {
        union { uint2 u; __bf16 h4[4]; } pk;
        #pragma unroll
        for (int r = 0; r < 4; ++r) pk.h4[r] = (__bf16)(oacc[ct][r] * rcp);
        *(uint2*)(o + orow + ct * 16 + lq * 4) = pk.u;
    }
}

extern "C" void kernel_launch(void* const* d_in, const int* in_sizes, int n_in,
                              void* d_out, int out_size, void* d_ws, size_t ws_size,
                              hipStream_t stream) {
    const float* tokens = (const float*)d_in[0];
    const float* gamma  = (const float*)d_in[1];
    const float* wq = (const float*)d_in[2];
    const float* wk = (const float*)d_in[3];
    const float* wv = (const float*)d_in[4];
    const float* wo = (const float*)d_in[5];

    __bf16* ws  = (__bf16*)d_ws;
    __bf16* x   = ws;                           // 4096*1024
    __bf16* qb  = x   + (size_t)4096 * 1024;
    __bf16* kb  = qb  + (size_t)4096 * 1024;
    __bf16* vtb = kb  + (size_t)4096 * 1024;    // V^T: 1024 x 4096
    __bf16* ao  = x;                            // alias: attn out reuses x's buffer
    __bf16* wob = qb;                           // alias: qb dead after attn
    float*  out = (float*)d_out;

    // bf16 Q/K/V weights stashed in d_out (consumed before final GEMM writes it)
    __bf16* wqb = (__bf16*)d_out;
    __bf16* wkb = wqb + (size_t)1024 * 1024;
    __bf16* wvb = wkb + (size_t)1024 * 1024;

    cvt_kernel<<<1024, 256, 0, stream>>>(wq, wqb);
    cvt_kernel<<<1024, 256, 0, stream>>>(wk, wkb);
    cvt_kernel<<<1024, 256, 0, stream>>>(wv, wvb);

    rmsnorm_kernel<<<4096, 256, 0, stream>>>(tokens, gamma, x);

    qkv_kernel<<<dim3(32, 8, 3), 256, 0, stream>>>(x, wqb, wkb, wvb, qb, kb, vtb);

    rope_kernel<<<8192, 256, 0, stream>>>(qb);
    rope_kernel<<<8192, 256, 0, stream>>>(kb);

    attn_kernel<<<1024, 256, 0, stream>>>(qb, kb, vtb, ao);

    cvt_kernel<<<1024, 256, 0, stream>>>(wo, wob);   // qb region is dead now

    wo_kernel<<<dim3(32, 8), 256, 0, stream>>>(ao, wob, out);
}

// Round 11
// 214.978 us; speedup vs baseline: 1.2226x; 1.0447x over previous
//
#include <hip/hip_runtime.h>

typedef __bf16 bf16x8 __attribute__((ext_vector_type(8)));
typedef float f32x4 __attribute__((ext_vector_type(4)));

#define DIM 1024
#define NSEQ 2048

// async 16B global -> LDS DMA (lane-linear: wave-uniform LDS base + lane*16)
#define GL2LDS(g, l) __builtin_amdgcn_global_load_lds( \
    (const __attribute__((address_space(1))) void*)(g), \
    (__attribute__((address_space(3))) void*)(l), 16, 0, 0)

// ---------------- fp32 -> bf16 weight conversion ----------------
__global__ __launch_bounds__(256) void cvt_kernel(const float* __restrict__ s,
                                                  __bf16* __restrict__ d) {
    int i = (blockIdx.x * 256 + threadIdx.x) * 4;
    float4 f = *(const float4*)(s + i);
    union { uint2 u; __bf16 h[4]; } p;
    p.h[0] = (__bf16)f.x; p.h[1] = (__bf16)f.y;
    p.h[2] = (__bf16)f.z; p.h[3] = (__bf16)f.w;
    *(uint2*)(d + i) = p.u;
}

// ---------------- RMSNorm: fp32 in, bf16 out ----------------
__global__ __launch_bounds__(256) void rmsnorm_kernel(const float* __restrict__ x,
                                                      const float* __restrict__ g,
                                                      __bf16* __restrict__ o) {
    int row = blockIdx.x;
    int t = threadIdx.x;
    float4 xv = ((const float4*)(x + (size_t)row * DIM))[t];
    float ss = xv.x*xv.x + xv.y*xv.y + xv.z*xv.z + xv.w*xv.w;
    #pragma unroll
    for (int off = 32; off; off >>= 1) ss += __shfl_xor(ss, off, 64);
    __shared__ float red[4];
    if ((t & 63) == 0) red[t >> 6] = ss;
    __syncthreads();
    ss = red[0] + red[1] + red[2] + red[3];
    float r = rsqrtf(ss * (1.0f / 1024.0f) + 1.1920929e-07f);
    float4 gv = ((const float4*)g)[t];
    union { uint2 u; __bf16 h[4]; } p;
    p.h[0] = (__bf16)(xv.x * r * gv.x);
    p.h[1] = (__bf16)(xv.y * r * gv.y);
    p.h[2] = (__bf16)(xv.z * r * gv.z);
    p.h[3] = (__bf16)(xv.w * r * gv.w);
    *(uint2*)(o + (size_t)row * DIM + t * 4) = p.u;
}

// ---------------- RoPE in-place on (4096 x 1024) bf16, heads of 64 ----------------
__global__ __launch_bounds__(256) void rope_kernel(__bf16* __restrict__ x) {
    int gid = blockIdx.x * 256 + threadIdx.x;   // one pair per thread
    int row = gid >> 9;          // 512 pairs per row
    int pr = gid & 511;
    int pos = row & (NSEQ - 1);
    int dp = pr & 31;            // pair index within head
    float inv = __expf(-(float)dp * (9.210340371976184f / 32.0f)); // 10000^(-2dp/64)
    float ang = (float)pos * inv;
    float sn, cs;
    sincosf(ang, &sn, &cs);
    size_t off = (size_t)row * DIM + pr * 2;
    union { unsigned int u; __bf16 h[2]; } p;
    p.u = *(const unsigned int*)(x + off);
    float x1 = (float)p.h[0], x2 = (float)p.h[1];
    p.h[0] = (__bf16)(x1 * cs - x2 * sn);
    p.h[1] = (__bf16)(x2 * cs + x1 * sn);
    *(unsigned int*)(x + off) = p.u;
}

// ---------------- shared GEMM body: C[i,j] = scale*sum_k A[mb*128+i,k]B[nb*128+j,k]
// 128x128 tile, BK=32, unpadded stride-32 LDS via global_load_lds, 2 barriers/tile.
template <typename CT>
__device__ __forceinline__ void gemm_body(const __bf16* __restrict__ A,
                                          const __bf16* __restrict__ B,
                                          CT* __restrict__ C,
                                          int mb, int nb, int ldc, float scale,
                                          __bf16* As, __bf16* Bs) {
    int t = threadIdx.x;
    int w = t >> 6, l = t & 63;
    int wm = (w >> 1) * 64, wn = (w & 1) * 64;   // wave 2x2 grid, each 64x64
    int lrow = l & 15, lq = l >> 4;
    f32x4 acc[4][4] = {};

    int srow = w * 16 + (l >> 2);                // DMA: + c*64
    int sc8 = (l & 3) * 8;
    const __bf16* gA = A + (size_t)(mb * 128 + srow) * 1024 + sc8;
    const __bf16* gB = B + (size_t)(nb * 128 + srow) * 1024 + sc8;
    __bf16* lA = As + (w * 64) * 8;              // lane-linear slots; + c*256*8
    __bf16* lB = Bs + (w * 64) * 8;

    for (int kt = 0; kt < 32; ++kt) {
        int k0 = kt * 32;
        GL2LDS(gA + k0, lA);
        GL2LDS(gA + k0 + (size_t)64 * 1024, lA + 256 * 8);
        GL2LDS(gB + k0, lB);
        GL2LDS(gB + k0 + (size_t)64 * 1024, lB + 256 * 8);
        __syncthreads();    // drains DMA, publishes tile
        bf16x8 af[4], bfr[4];
        #pragma unroll
        for (int i = 0; i < 4; ++i)
            af[i] = *(const bf16x8*)&As[(wm + i * 16 + lrow) * 32 + lq * 8];
        #pragma unroll
        for (int i = 0; i < 4; ++i)
            bfr[i] = *(const bf16x8*)&Bs[(wn + i * 16 + lrow) * 32 + lq * 8];
        #pragma unroll
        for (int rt = 0; rt < 4; ++rt)
            #pragma unroll
            for (int ct = 0; ct < 4; ++ct)
                acc[rt][ct] = __builtin_amdgcn_mfma_f32_16x16x32_bf16(
                    af[rt], bfr[ct], acc[rt][ct], 0, 0, 0);
        __syncthreads();
    }
    #pragma unroll
    for (int rt = 0; rt < 4; ++rt)
        #pragma unroll
        for (int ct = 0; ct < 4; ++ct)
            #pragma unroll
            for (int r = 0; r < 4; ++r) {
                int row = mb * 128 + wm + rt * 16 + lq * 4 + r;   // C-layout
                int col = nb * 128 + wn + ct * 16 + lrow;
                C[(size_t)row * ldc + col] = (CT)(acc[rt][ct][r] * scale);
            }
}

// Fused QKV projections: grid (32, 8, 3) -> 768 blocks = 3 blocks/CU.
__global__ __launch_bounds__(256) void qkv_kernel(const __bf16* __restrict__ x,
                                                  const __bf16* __restrict__ wq,
                                                  const __bf16* __restrict__ wk,
                                                  const __bf16* __restrict__ wv,
                                                  __bf16* __restrict__ qb,
                                                  __bf16* __restrict__ kb,
                                                  __bf16* __restrict__ vtb) {
    __shared__ __bf16 As[128 * 32];
    __shared__ __bf16 Bs[128 * 32];
    int bm = blockIdx.x, bn = blockIdx.y, z = blockIdx.z;
    if (z == 0)      gemm_body<__bf16>(x,  wq, qb,  bm, bn, 1024, 0.125f, As, Bs);
    else if (z == 1) gemm_body<__bf16>(x,  wk, kb,  bm, bn, 1024, 1.0f,   As, Bs);
    else             gemm_body<__bf16>(wv, x,  vtb, bn, bm, 4096, 1.0f,   As, Bs);
}

// Output projection: all-bf16 DMA path, fp32 store.
__global__ __launch_bounds__(256) void wo_kernel(const __bf16* __restrict__ A,
                                                 const __bf16* __restrict__ B,
                                                 float* __restrict__ C) {
    __shared__ __bf16 As[128 * 32];
    __shared__ __bf16 Bs[128 * 32];
    gemm_body<float>(A, B, C, blockIdx.x, blockIdx.y, 1024, 1.0f, As, Bs);
}

// ---------------- Causal flash attention (S^T, 128-row Q-tiles) ----------------
// q,k: (4096 x 1024) bf16; vt: (1024 x 4096) bf16 (V pre-transposed).
// 512 blocks; XCD swizzle pins 4 (b,h) per XCD for K/V L2 residency.
// Each wave handles 32 q-rows (two 16-col B-frag groups); K/V tiles of 64 keys.
__global__ __launch_bounds__(256, 3) void attn_kernel(const __bf16* __restrict__ q,
                                                      const __bf16* __restrict__ kk,
                                                      const __bf16* __restrict__ vt,
                                                      __bf16* __restrict__ o) {
    int id = blockIdx.x;
    int xcd = id & 7;                    // dispatch round-robins over 8 XCDs
    int slot = id >> 3;                  // 0..63 within XCD
    int qt = 15 - (slot >> 2);           // long q-tiles dispatch first
    int bh = xcd * 4 + (slot & 3);       // 4 (b,h) pairs resident per XCD
    int h = bh & 15;
    int b = bh >> 4;
    int Q0 = qt * 128;
    int rowbase = b * NSEQ;
    int t = threadIdx.x;
    int w = t >> 6, l = t & 63;
    int lrow = l & 15, lq = l >> 4;

    __shared__ __bf16 Kt[64 * 72];       // [key][d], stride 72
    __shared__ __bf16 Vs[64 * 72];       // [d][key], stride 72 (from vt)
    __shared__ __bf16 Ps[4 * 32 * 72];   // per-wave P^T strip [32 qrows][64 keys]
    __bf16* pw = &Ps[w * 32 * 72];

    const __bf16* kbase = kk + (size_t)rowbase * DIM + h * 64;
    const __bf16* vbase = vt + (size_t)(h * 64) * 4096 + b * 2048;

    int row0 = t >> 3;
    int c8 = (t & 7) * 8;

    // Q B-frags for col groups g=0,1: qrow = Q0 + w*32 + g*16 + lrow
    const __bf16* qp0 = q + (size_t)(rowbase + Q0 + w * 32 + lrow) * DIM + h * 64;
    bf16x8 qb00 = *(const bf16x8*)(qp0 + lq * 8);
    bf16x8 qb01 = *(const bf16x8*)(qp0 + 32 + lq * 8);
    bf16x8 qb10 = *(const bf16x8*)(qp0 + 16 * DIM + lq * 8);
    bf16x8 qb11 = *(const bf16x8*)(qp0 + 16 * DIM + 32 + lq * 8);

    f32x4 oacc[2][4] = {};               // [g][d-chunk], col = qrow
    float m_r[2] = {-1e30f, -1e30f}, l_r[2] = {0.0f, 0.0f};

    uint4 kr0, kr1, vr0, vr1;
    kr0 = *(const uint4*)(kbase + (size_t)row0 * DIM + c8);
    kr1 = *(const uint4*)(kbase + (size_t)(row0 + 32) * DIM + c8);
    vr0 = *(const uint4*)(vbase + (size_t)row0 * 4096 + c8);
    vr1 = *(const uint4*)(vbase + (size_t)(row0 + 32) * 4096 + c8);
    *(uint4*)&Kt[row0 * 72 + c8] = kr0;
    *(uint4*)&Kt[(row0 + 32) * 72 + c8] = kr1;
    *(uint4*)&Vs[row0 * 72 + c8] = vr0;
    *(uint4*)&Vs[(row0 + 32) * 72 + c8] = vr1;
    __syncthreads();

    int T = 2 * qt + 2;                  // K-tiles: keys [0, Q0+128)
    for (int jt = 0; jt < T; ++jt) {
        int j0 = jt * 64;
        if (jt + 1 < T) {
            int jn = j0 + 64;
            kr0 = *(const uint4*)(kbase + (size_t)(jn + row0) * DIM + c8);
            kr1 = *(const uint4*)(kbase + (size_t)(jn + row0 + 32) * DIM + c8);
            vr0 = *(const uint4*)(vbase + (size_t)row0 * 4096 + jn + c8);
            vr1 = *(const uint4*)(vbase + (size_t)(row0 + 32) * 4096 + jn + c8);
        }
        // wave-uniform skip: all 32 qrows of this wave fully masked on this tile
        bool active = (j0 <= Q0 + w * 32 + 31);
        if (active) {
            // S^T: A = K[m=key][k=d] (shared across g), B = Q group g
            f32x4 st[2][4];
            #pragma unroll
            for (int ct = 0; ct < 4; ++ct) {
                bf16x8 ka0 = *(const bf16x8*)&Kt[(ct * 16 + lrow) * 72 + lq * 8];
                bf16x8 ka1 = *(const bf16x8*)&Kt[(ct * 16 + lrow) * 72 + 32 + lq * 8];
                f32x4 z0 = {}, z1 = {};
                z0 = __builtin_amdgcn_mfma_f32_16x16x32_bf16(ka0, qb00, z0, 0, 0, 0);
                z0 = __builtin_amdgcn_mfma_f32_16x16x32_bf16(ka1, qb01, z0, 0, 0, 0);
                z1 = __builtin_amdgcn_mfma_f32_16x16x32_bf16(ka0, qb10, z1, 0, 0, 0);
                z1 = __builtin_amdgcn_mfma_f32_16x16x32_bf16(ka1, qb11, z1, 0, 0, 0);
                st[0][ct] = z0;
                st[1][ct] = z1;
            }
            // causal mask (only tiles overlapping/above the diagonal)
            if (jt >= 2 * qt) {
                #pragma unroll
                for (int g = 0; g < 2; ++g) {
                    int qr = Q0 + w * 32 + g * 16 + lrow;
                    #pragma unroll
                    for (int ct = 0; ct < 4; ++ct)
                        #pragma unroll
                        for (int r = 0; r < 4; ++r)
                            if (j0 + ct * 16 + lq * 4 + r > qr) st[g][ct][r] = -3.0e38f;
                }
            }
            // per-lane online softmax per group
            #pragma unroll
            for (int g = 0; g < 2; ++g) {
                float mx = st[g][0][0];
                #pragma unroll
                for (int ct = 0; ct < 4; ++ct)
                    #pragma unroll
                    for (int r = 0; r < 4; ++r) mx = fmaxf(mx, st[g][ct][r]);
                mx = fmaxf(mx, __shfl_xor(mx, 16, 64));
                mx = fmaxf(mx, __shfl_xor(mx, 32, 64));
                float mnew = fmaxf(m_r[g], mx);
                float alpha = __expf(m_r[g] - mnew);
                float ps = 0.0f;
                #pragma unroll
                for (int ct = 0; ct < 4; ++ct)
                    #pragma unroll
                    for (int r = 0; r < 4; ++r) {
                        float p = __expf(st[g][ct][r] - mnew);
                        st[g][ct][r] = p;
                        ps += p;
                    }
                ps += __shfl_xor(ps, 16, 64);
                ps += __shfl_xor(ps, 32, 64);
                l_r[g] = l_r[g] * alpha + ps;
                m_r[g] = mnew;
                // P^T -> per-wave strip, 4x ds_write_b64 per group
                #pragma unroll
                for (int ct = 0; ct < 4; ++ct) {
                    union { uint2 u; __bf16 h4[4]; } pk;
                    #pragma unroll
                    for (int r = 0; r < 4; ++r) pk.h4[r] = (__bf16)st[g][ct][r];
                    *(uint2*)&pw[(g * 16 + lrow) * 72 + ct * 16 + lq * 4] = pk.u;
                }
                #pragma unroll
                for (int ct = 0; ct < 4; ++ct)
                    #pragma unroll
                    for (int r = 0; r < 4; ++r) oacc[g][ct][r] *= alpha;
            }
            // O^T += V^T * P^T (va shared across g)
            bf16x8 pb00 = *(const bf16x8*)&pw[lrow * 72 + lq * 8];
            bf16x8 pb01 = *(const bf16x8*)&pw[lrow * 72 + 32 + lq * 8];
            bf16x8 pb10 = *(const bf16x8*)&pw[(16 + lrow) * 72 + lq * 8];
            bf16x8 pb11 = *(const bf16x8*)&pw[(16 + lrow) * 72 + 32 + lq * 8];
            #pragma unroll
            for (int ct = 0; ct < 4; ++ct) {
                bf16x8 va0 = *(const bf16x8*)&Vs[(ct * 16 + lrow) * 72 + lq * 8];
                bf16x8 va1 = *(const bf16x8*)&Vs[(ct * 16 + lrow) * 72 + 32 + lq * 8];
                oacc[0][ct] = __builtin_amdgcn_mfma_f32_16x16x32_bf16(va0, pb00, oacc[0][ct], 0, 0, 0);
                oacc[0][ct] = __builtin_amdgcn_mfma_f32_16x16x32_bf16(va1, pb01, oacc[0][ct], 0, 0, 0);
                oacc[1][ct] = __builtin_amdgcn_mfma_f32_16x16x32_bf16(va0, pb10, oacc[1][ct], 0, 0, 0);
                oacc[1][ct] = __builtin_amdgcn_mfma_f32_16x16x32_bf16(va1, pb11, oacc[1][ct], 0, 0, 0);
            }
        }
        __syncthreads();                 // all waves done reading Kt/Vs
        if (jt + 1 < T) {
            *(uint4*)&Kt[row0 * 72 + c8] = kr0;
            *(uint4*)&Kt[(row0 + 32) * 72 + c8] = kr1;
            *(uint4*)&Vs[row0 * 72 + c8] = vr0;
            *(uint4*)&Vs[(row0 + 32) * 72 + c8] = vr1;
        }
        __syncthreads();
    }
    // epilogue
    #pragma unroll
    for (int g = 0; g < 2; ++g) {
        float rcp = 1.0f / l_r[g];
        const size_t orow = (size_t)(rowbase + Q0 + w * 32 + g * 16 + lrow) * DIM + h * 64;
        #pragma unroll
        for (int ct = 0; ct < 4; ++ct) {
            union { uint2 u; __bf16 h4[4]; } pk;
            #pragma unroll
            for (int r = 0; r < 4; ++r) pk.h4[r] = (__bf16)(oacc[g][ct][r] * rcp);
            *(uint2*)(o + orow + ct * 16 + lq * 4) = pk.u;
        }
    }
}

extern "C" void kernel_launch(void* const* d_in, const int* in_sizes, int n_in,
                              void* d_out, int out_size, void* d_ws, size_t ws_size,
                              hipStream_t stream) {
    const float* tokens = (const float*)d_in[0];
    const float* gamma  = (const float*)d_in[1];
    const float* wq = (const float*)d_in[2];
    const float* wk = (const float*)d_in[3];
    const float* wv = (const float*)d_in[4];
    const float* wo = (const float*)d_in[5];

    __bf16* ws  = (__bf16*)d_ws;
    __bf16* x   = ws;                           // 4096*1024
    __bf16* qb  = x   + (size_t)4096 * 1024;
    __bf16* kb  = qb  + (size_t)4096 * 1024;
    __bf16* vtb = kb  + (size_t)4096 * 1024;    // V^T: 1024 x 4096
    __bf16* ao  = x;                            // alias: attn out reuses x's buffer
    __bf16* wob = qb;                           // alias: qb dead after attn
    float*  out = (float*)d_out;

    // bf16 Q/K/V weights stashed in d_out (consumed before final GEMM writes it)
    __bf16* wqb = (__bf16*)d_out;
    __bf16* wkb = wqb + (size_t)1024 * 1024;
    __bf16* wvb = wkb + (size_t)1024 * 1024;

    cvt_kernel<<<1024, 256, 0, stream>>>(wq, wqb);
    cvt_kernel<<<1024, 256, 0, stream>>>(wk, wkb);
    cvt_kernel<<<1024, 256, 0, stream>>>(wv, wvb);

    rmsnorm_kernel<<<4096, 256, 0, stream>>>(tokens, gamma, x);

    qkv_kernel<<<dim3(32, 8, 3), 256, 0, stream>>>(x, wqb, wkb, wvb, qb, kb, vtb);

    rope_kernel<<<8192, 256, 0, stream>>>(qb);
    rope_kernel<<<8192, 256, 0, stream>>>(kb);

    attn_kernel<<<512, 256, 0, stream>>>(qb, kb, vtb, ao);

    cvt_kernel<<<1024, 256, 0, stream>>>(wo, wob);   // qb region is dead now

    wo_kernel<<<dim3(32, 8), 256, 0, stream>>>(ao, wob, out);
}

// Round 12
// 214.930 us; speedup vs baseline: 1.2228x; 1.0002x over previous
//
#include <hip/hip_runtime.h>

typedef __bf16 bf16x8 __attribute__((ext_vector_type(8)));
typedef float f32x4 __attribute__((ext_vector_type(4)));

#define DIM 1024
#define NSEQ 2048

// async 16B global -> LDS DMA (lane-linear: wave-uniform LDS base + lane*16)
#define GL2LDS(g, l) __builtin_amdgcn_global_load_lds( \
    (const __attribute__((address_space(1))) void*)(g), \
    (__attribute__((address_space(3))) void*)(l), 16, 0, 0)

// ---------------- fp32 -> bf16 weight conversion ----------------
__global__ __launch_bounds__(256) void cvt_kernel(const float* __restrict__ s,
                                                  __bf16* __restrict__ d) {
    int i = (blockIdx.x * 256 + threadIdx.x) * 4;
    float4 f = *(const float4*)(s + i);
    union { uint2 u; __bf16 h[4]; } p;
    p.h[0] = (__bf16)f.x; p.h[1] = (__bf16)f.y;
    p.h[2] = (__bf16)f.z; p.h[3] = (__bf16)f.w;
    *(uint2*)(d + i) = p.u;
}

// ---------------- zero the 8 per-XCD work-queue counters ----------------
__global__ void init_kernel(int* c) { c[threadIdx.x] = 0; }

// ---------------- RMSNorm: fp32 in, bf16 out ----------------
__global__ __launch_bounds__(256) void rmsnorm_kernel(const float* __restrict__ x,
                                                      const float* __restrict__ g,
                                                      __bf16* __restrict__ o) {
    int row = blockIdx.x;
    int t = threadIdx.x;
    float4 xv = ((const float4*)(x + (size_t)row * DIM))[t];
    float ss = xv.x*xv.x + xv.y*xv.y + xv.z*xv.z + xv.w*xv.w;
    #pragma unroll
    for (int off = 32; off; off >>= 1) ss += __shfl_xor(ss, off, 64);
    __shared__ float red[4];
    if ((t & 63) == 0) red[t >> 6] = ss;
    __syncthreads();
    ss = red[0] + red[1] + red[2] + red[3];
    float r = rsqrtf(ss * (1.0f / 1024.0f) + 1.1920929e-07f);
    float4 gv = ((const float4*)g)[t];
    union { uint2 u; __bf16 h[4]; } p;
    p.h[0] = (__bf16)(xv.x * r * gv.x);
    p.h[1] = (__bf16)(xv.y * r * gv.y);
    p.h[2] = (__bf16)(xv.z * r * gv.z);
    p.h[3] = (__bf16)(xv.w * r * gv.w);
    *(uint2*)(o + (size_t)row * DIM + t * 4) = p.u;
}

// ---------------- RoPE in-place on (4096 x 1024) bf16, heads of 64 ----------------
__global__ __launch_bounds__(256) void rope_kernel(__bf16* __restrict__ x) {
    int gid = blockIdx.x * 256 + threadIdx.x;   // one pair per thread
    int row = gid >> 9;          // 512 pairs per row
    int pr = gid & 511;
    int pos = row & (NSEQ - 1);
    int dp = pr & 31;            // pair index within head
    float inv = __expf(-(float)dp * (9.210340371976184f / 32.0f)); // 10000^(-2dp/64)
    float ang = (float)pos * inv;
    float sn, cs;
    sincosf(ang, &sn, &cs);
    size_t off = (size_t)row * DIM + pr * 2;
    union { unsigned int u; __bf16 h[2]; } p;
    p.u = *(const unsigned int*)(x + off);
    float x1 = (float)p.h[0], x2 = (float)p.h[1];
    p.h[0] = (__bf16)(x1 * cs - x2 * sn);
    p.h[1] = (__bf16)(x2 * cs + x1 * sn);
    *(unsigned int*)(x + off) = p.u;
}

// ---------------- shared GEMM body: C[i,j] = scale*sum_k A[mb*128+i,k]B[nb*128+j,k]
// 128x128 tile, BK=64 (16 barrier-pairs instead of 32), unpadded stride-64 LDS
// filled by global_load_lds, single buffer.
template <typename CT>
__device__ __forceinline__ void gemm_body(const __bf16* __restrict__ A,
                                          const __bf16* __restrict__ B,
                                          CT* __restrict__ C,
                                          int mb, int nb, int ldc, float scale,
                                          __bf16* As, __bf16* Bs) {
    int t = threadIdx.x;
    int w = t >> 6, l = t & 63;
    int wm = (w >> 1) * 64, wn = (w & 1) * 64;   // wave 2x2 grid, each 64x64
    int lrow = l & 15, lq = l >> 4;
    f32x4 acc[4][4] = {};

    // DMA geometry: call c (0..3), wave w, lane l -> tile row w*32 + c*8 + (l>>3),
    // col block (l&7)*8. LDS base per (w,c) lane-uniform; HW adds lane*16B.
    int srow = w * 32 + (l >> 3);
    int sc8 = (l & 7) * 8;
    const __bf16* gA = A + (size_t)(mb * 128 + srow) * 1024 + sc8;
    const __bf16* gB = B + (size_t)(nb * 128 + srow) * 1024 + sc8;
    __bf16* lA = As + (size_t)(w * 32) * 64;     // + c*8*64
    __bf16* lB = Bs + (size_t)(w * 32) * 64;

    for (int kt = 0; kt < 16; ++kt) {
        int k0 = kt * 64;
        #pragma unroll
        for (int c = 0; c < 4; ++c) {
            GL2LDS(gA + (size_t)c * 8 * 1024 + k0, lA + c * 8 * 64);
            GL2LDS(gB + (size_t)c * 8 * 1024 + k0, lB + c * 8 * 64);
        }
        __syncthreads();    // drains DMA, publishes tile
        #pragma unroll
        for (int ch = 0; ch < 2; ++ch) {
            bf16x8 af[4], bfr[4];
            #pragma unroll
            for (int i = 0; i < 4; ++i)
                af[i] = *(const bf16x8*)&As[(wm + i * 16 + lrow) * 64 + ch * 32 + lq * 8];
            #pragma unroll
            for (int i = 0; i < 4; ++i)
                bfr[i] = *(const bf16x8*)&Bs[(wn + i * 16 + lrow) * 64 + ch * 32 + lq * 8];
            #pragma unroll
            for (int rt = 0; rt < 4; ++rt)
                #pragma unroll
                for (int ct = 0; ct < 4; ++ct)
                    acc[rt][ct] = __builtin_amdgcn_mfma_f32_16x16x32_bf16(
                        af[rt], bfr[ct], acc[rt][ct], 0, 0, 0);
        }
        __syncthreads();
    }
    #pragma unroll
    for (int rt = 0; rt < 4; ++rt)
        #pragma unroll
        for (int ct = 0; ct < 4; ++ct)
            #pragma unroll
            for (int r = 0; r < 4; ++r) {
                int row = mb * 128 + wm + rt * 16 + lq * 4 + r;   // C-layout
                int col = nb * 128 + wn + ct * 16 + lrow;
                C[(size_t)row * ldc + col] = (CT)(acc[rt][ct][r] * scale);
            }
}

// Fused QKV projections: grid (32, 8, 3) -> 768 blocks = 3 blocks/CU.
__global__ __launch_bounds__(256) void qkv_kernel(const __bf16* __restrict__ x,
                                                  const __bf16* __restrict__ wq,
                                                  const __bf16* __restrict__ wk,
                                                  const __bf16* __restrict__ wv,
                                                  __bf16* __restrict__ qb,
                                                  __bf16* __restrict__ kb,
                                                  __bf16* __restrict__ vtb) {
    __shared__ __bf16 As[128 * 64];
    __shared__ __bf16 Bs[128 * 64];
    int bm = blockIdx.x, bn = blockIdx.y, z = blockIdx.z;
    if (z == 0)      gemm_body<__bf16>(x,  wq, qb,  bm, bn, 1024, 0.125f, As, Bs);
    else if (z == 1) gemm_body<__bf16>(x,  wk, kb,  bm, bn, 1024, 1.0f,   As, Bs);
    else             gemm_body<__bf16>(wv, x,  vtb, bn, bm, 4096, 1.0f,   As, Bs);
}

// Output projection: all-bf16 DMA path, fp32 store.
__global__ __launch_bounds__(256) void wo_kernel(const __bf16* __restrict__ A,
                                                 const __bf16* __restrict__ B,
                                                 float* __restrict__ C) {
    __shared__ __bf16 As[128 * 64];
    __shared__ __bf16 Bs[128 * 64];
    gemm_body<float>(A, B, C, blockIdx.x, blockIdx.y, 1024, 1.0f, As, Bs);
}

// ---------------- Causal flash attention: persistent blocks + per-XCD queues ----
// q,k: (4096 x 1024) bf16; vt: (1024 x 4096) bf16 (V pre-transposed).
// 512 persistent blocks (2/CU). Work item = (bh, 64-row q-tile), long-first,
// pulled from the block's XCD counter -> placement-independent LPT balance +
// K/V L2 residency (4 bh per XCD). K/V double-buffered: ONE barrier per iter.
__global__ __launch_bounds__(256, 2) void attn_kernel(const __bf16* __restrict__ q,
                                                      const __bf16* __restrict__ kk,
                                                      const __bf16* __restrict__ vt,
                                                      __bf16* __restrict__ o,
                                                      int* __restrict__ counters) {
    int xcd = blockIdx.x & 7;            // dispatch round-robins over XCDs
    int t = threadIdx.x;
    int w = t >> 6, l = t & 63;
    int lrow = l & 15, lq = l >> 4;
    int row0 = t >> 3;
    int c8 = (t & 7) * 8;

    __shared__ __bf16 Kt[2][64 * 72];    // [key][d], stride 72
    __shared__ __bf16 Vs[2][64 * 72];    // [d][key], stride 72 (from vt)
    __shared__ __bf16 Ps[4 * 16 * 72];   // per-wave P^T strip [qrow][key]
    __shared__ int s_item;
    __bf16* pw = &Ps[w * 16 * 72];

    for (;;) {
        if (t == 0) s_item = atomicAdd(&counters[xcd], 1);
        __syncthreads();                 // broadcast item; also fences LDS reuse
        int item = s_item;
        if (item >= 128) break;
        int qt = 31 - (item >> 2);       // long q-tiles first (LPT)
        int bh = xcd * 4 + (item & 3);   // 4 (b,h) pairs resident per XCD
        int h = bh & 15;
        int b = bh >> 4;
        int rowbase = b * NSEQ;

        const __bf16* kbase = kk + (size_t)rowbase * DIM + h * 64;
        const __bf16* vbase = vt + (size_t)(h * 64) * 4096 + b * 2048;

        // Q as B-fragment: B[n=qrow=l&15][k=d=(l>>4)*8+j]
        const __bf16* qp = q + (size_t)(rowbase + qt * 64 + w * 16 + lrow) * DIM + h * 64;
        bf16x8 qb0 = *(const bf16x8*)(qp + lq * 8);
        bf16x8 qb1 = *(const bf16x8*)(qp + 32 + lq * 8);

        f32x4 oacc[4] = {};              // O^T: [d-chunk], col = qrow
        float m_r = -1e30f, l_r = 0.0f;  // per-lane scalars (qrow = lrow)

        // stage tile 0 into buffer 0 (explicit named regs -> no scratch)
        uint4 kr0, kr1, vr0, vr1;
        kr0 = *(const uint4*)(kbase + (size_t)row0 * DIM + c8);
        kr1 = *(const uint4*)(kbase + (size_t)(row0 + 32) * DIM + c8);
        vr0 = *(const uint4*)(vbase + (size_t)row0 * 4096 + c8);
        vr1 = *(const uint4*)(vbase + (size_t)(row0 + 32) * 4096 + c8);
        *(uint4*)&Kt[0][row0 * 72 + c8] = kr0;
        *(uint4*)&Kt[0][(row0 + 32) * 72 + c8] = kr1;
        *(uint4*)&Vs[0][row0 * 72 + c8] = vr0;
        *(uint4*)&Vs[0][(row0 + 32) * 72 + c8] = vr1;
        __syncthreads();

        for (int jt = 0; jt <= qt; ++jt) {
            int cur = jt & 1;
            if (jt < qt) {               // register prefetch of next K/V tile
                int j0 = (jt + 1) * 64;
                kr0 = *(const uint4*)(kbase + (size_t)(j0 + row0) * DIM + c8);
                kr1 = *(const uint4*)(kbase + (size_t)(j0 + row0 + 32) * DIM + c8);
                vr0 = *(const uint4*)(vbase + (size_t)row0 * 4096 + j0 + c8);
                vr1 = *(const uint4*)(vbase + (size_t)(row0 + 32) * 4096 + j0 + c8);
            }
            // S^T strip (64 keys x 16 qrows): A = K[m=key][k=d], B = Q
            f32x4 st[4];
            #pragma unroll
            for (int ct = 0; ct < 4; ++ct) {
                f32x4 z = {};
                bf16x8 ka0 = *(const bf16x8*)&Kt[cur][(ct * 16 + lrow) * 72 + lq * 8];
                bf16x8 ka1 = *(const bf16x8*)&Kt[cur][(ct * 16 + lrow) * 72 + 32 + lq * 8];
                z = __builtin_amdgcn_mfma_f32_16x16x32_bf16(ka0, qb0, z, 0, 0, 0);
                z = __builtin_amdgcn_mfma_f32_16x16x32_bf16(ka1, qb1, z, 0, 0, 0);
                st[ct] = z;              // key = ct*16+lq*4+r, qrow(local) = lrow
            }
            if (jt == qt) {              // causal mask on diagonal tile
                int qr = w * 16 + lrow;
                #pragma unroll
                for (int ct = 0; ct < 4; ++ct)
                    #pragma unroll
                    for (int r = 0; r < 4; ++r)
                        if (ct * 16 + lq * 4 + r > qr) st[ct][r] = -3.0e38f;
            }
            // per-lane online softmax (2 shuffles)
            float mx = st[0][0];
            #pragma unroll
            for (int ct = 0; ct < 4; ++ct)
                #pragma unroll
                for (int r = 0; r < 4; ++r) mx = fmaxf(mx, st[ct][r]);
            mx = fmaxf(mx, __shfl_xor(mx, 16, 64));
            mx = fmaxf(mx, __shfl_xor(mx, 32, 64));
            float mnew = fmaxf(m_r, mx);
            float alpha = __expf(m_r - mnew);
            float ps = 0.0f;
            #pragma unroll
            for (int ct = 0; ct < 4; ++ct)
                #pragma unroll
                for (int r = 0; r < 4; ++r) {
                    float p = __expf(st[ct][r] - mnew);
                    st[ct][r] = p;
                    ps += p;
                }
            ps += __shfl_xor(ps, 16, 64);
            ps += __shfl_xor(ps, 32, 64);
            l_r = l_r * alpha + ps;
            m_r = mnew;

            // P^T -> per-wave strip (same-wave reuse, no barrier)
            #pragma unroll
            for (int ct = 0; ct < 4; ++ct) {
                union { uint2 u; __bf16 h4[4]; } pk;
                #pragma unroll
                for (int r = 0; r < 4; ++r) pk.h4[r] = (__bf16)st[ct][r];
                *(uint2*)&pw[lrow * 72 + ct * 16 + lq * 4] = pk.u;
            }
            #pragma unroll
            for (int ct = 0; ct < 4; ++ct)
                #pragma unroll
                for (int r = 0; r < 4; ++r) oacc[ct][r] *= alpha;
            // O^T += V^T * P^T
            bf16x8 pb0 = *(const bf16x8*)&pw[lrow * 72 + lq * 8];
            bf16x8 pb1 = *(const bf16x8*)&pw[lrow * 72 + 32 + lq * 8];
            #pragma unroll
            for (int ct = 0; ct < 4; ++ct) {
                bf16x8 va0 = *(const bf16x8*)&Vs[cur][(ct * 16 + lrow) * 72 + lq * 8];
                bf16x8 va1 = *(const bf16x8*)&Vs[cur][(ct * 16 + lrow) * 72 + 32 + lq * 8];
                oacc[ct] = __builtin_amdgcn_mfma_f32_16x16x32_bf16(va0, pb0, oacc[ct], 0, 0, 0);
                oacc[ct] = __builtin_amdgcn_mfma_f32_16x16x32_bf16(va1, pb1, oacc[ct], 0, 0, 0);
            }
            // store prefetched tile into ALTERNATE buffer; safe pre-barrier:
            // other waves in this window only read buffer `cur`.
            if (jt < qt) {
                *(uint4*)&Kt[cur ^ 1][row0 * 72 + c8] = kr0;
                *(uint4*)&Kt[cur ^ 1][(row0 + 32) * 72 + c8] = kr1;
                *(uint4*)&Vs[cur ^ 1][row0 * 72 + c8] = vr0;
                *(uint4*)&Vs[cur ^ 1][(row0 + 32) * 72 + c8] = vr1;
            }
            __syncthreads();             // single barrier per iteration
        }
        // epilogue: O^T C-layout -> o[qrow][d]
        float rcp = 1.0f / l_r;
        const size_t orow = (size_t)(rowbase + qt * 64 + w * 16 + lrow) * DIM + h * 64;
        #pragma unroll
        for (int ct = 0; ct < 4; ++ct) {
            union { uint2 u; __bf16 h4[4]; } pk;
            #pragma unroll
            for (int r = 0; r < 4; ++r) pk.h4[r] = (__bf16)(oacc[ct][r] * rcp);
            *(uint2*)(o + orow + ct * 16 + lq * 4) = pk.u;
        }
    }
}

extern "C" void kernel_launch(void* const* d_in, const int* in_sizes, int n_in,
                              void* d_out, int out_size, void* d_ws, size_t ws_size,
                              hipStream_t stream) {
    const float* tokens = (const float*)d_in[0];
    const float* gamma  = (const float*)d_in[1];
    const float* wq = (const float*)d_in[2];
    const float* wk = (const float*)d_in[3];
    const float* wv = (const float*)d_in[4];
    const float* wo = (const float*)d_in[5];

    __bf16* ws  = (__bf16*)d_ws;
    __bf16* x   = ws;                           // 4096*1024
    __bf16* qb  = x   + (size_t)4096 * 1024;
    __bf16* kb  = qb  + (size_t)4096 * 1024;
    __bf16* vtb = kb  + (size_t)4096 * 1024;    // V^T: 1024 x 4096
    __bf16* ao  = x;                            // alias: attn out reuses x's buffer
    __bf16* wob = qb;                           // alias: qb dead after attn
    float*  out = (float*)d_out;

    // bf16 Q/K/V weights stashed in d_out (consumed by qkv before wo overwrites);
    // work-queue counters at d_out+8MB (written after qkv, dead before wo's C).
    __bf16* wqb = (__bf16*)d_out;
    __bf16* wkb = wqb + (size_t)1024 * 1024;
    __bf16* wvb = wkb + (size_t)1024 * 1024;
    int* counters = (int*)((char*)d_out + (size_t)8 * 1024 * 1024);

    cvt_kernel<<<1024, 256, 0, stream>>>(wq, wqb);
    cvt_kernel<<<1024, 256, 0, stream>>>(wk, wkb);
    cvt_kernel<<<1024, 256, 0, stream>>>(wv, wvb);

    rmsnorm_kernel<<<4096, 256, 0, stream>>>(tokens, gamma, x);

    qkv_kernel<<<dim3(32, 8, 3), 256, 0, stream>>>(x, wqb, wkb, wvb, qb, kb, vtb);

    rope_kernel<<<8192, 256, 0, stream>>>(qb);
    rope_kernel<<<8192, 256, 0, stream>>>(kb);

    init_kernel<<<1, 8, 0, stream>>>(counters);

    attn_kernel<<<512, 256, 0, stream>>>(qb, kb, vtb, ao, counters);

    cvt_kernel<<<1024, 256, 0, stream>>>(wo, wob);   // qb region is dead now

    wo_kernel<<<dim3(32, 8), 256, 0, stream>>>(ao, wob, out);
}